// Round 1
// baseline (478.725 us; speedup 1.0000x reference)
//
#include <hip/hip_runtime.h>

#define DIM 64

// Phase 1: emb_sum[e*64+d] = hw[widx[0][e][d]] + hw[widx[1][e][d]]
__global__ void emb_sum_kernel(const int* __restrict__ widx,
                               const float* __restrict__ hw,
                               float* __restrict__ esum,
                               long long total /* num_emb*DIM */) {
    long long gid = (long long)blockIdx.x * blockDim.x + threadIdx.x;
    if (gid >= total) return;
    int i0 = widx[gid];
    int i1 = widx[gid + total];
    esum[gid] = hw[i0] + hw[i1];
}

// Phase 2: one wave per bag; lane = dim. out[b][d] = sum_t esum[x[t]*64+d]
__global__ void bag_sum_kernel(const int* __restrict__ x,
                               const int* __restrict__ offsets,
                               const float* __restrict__ esum,
                               float* __restrict__ out,
                               int num_bags, int total_tokens) {
    int wave = (int)((blockIdx.x * blockDim.x + threadIdx.x) >> 6);
    int lane = threadIdx.x & 63;
    if (wave >= num_bags) return;
    int start = offsets[wave];
    int end = (wave + 1 < num_bags) ? offsets[wave + 1] : total_tokens;

    float acc = 0.0f;
    for (int base = start; base < end; base += 64) {
        int n = end - base;
        if (n > 64) n = 64;
        int xv = (lane < n) ? x[base + lane] : 0;
        for (int t = 0; t < n; ++t) {
            int e = __shfl(xv, t, 64);
            acc += esum[(size_t)e * DIM + lane];
        }
    }
    out[(size_t)wave * DIM + lane] = acc;
}

// Fallback: direct gather (no workspace). One wave per bag.
__global__ void direct_kernel(const int* __restrict__ x,
                              const int* __restrict__ offsets,
                              const float* __restrict__ hw,
                              const int* __restrict__ widx,
                              float* __restrict__ out,
                              int num_bags, int total_tokens,
                              long long emb_total /* num_emb*DIM */) {
    int wave = (int)((blockIdx.x * blockDim.x + threadIdx.x) >> 6);
    int lane = threadIdx.x & 63;
    if (wave >= num_bags) return;
    int start = offsets[wave];
    int end = (wave + 1 < num_bags) ? offsets[wave + 1] : total_tokens;

    float acc = 0.0f;
    for (int t = start; t < end; ++t) {
        int e = x[t];
        const int* row = widx + (size_t)e * DIM;
        int i0 = row[lane];
        int i1 = row[emb_total + lane];
        acc += hw[i0] + hw[i1];
    }
    out[(size_t)wave * DIM + lane] = acc;
}

extern "C" void kernel_launch(void* const* d_in, const int* in_sizes, int n_in,
                              void* d_out, int out_size, void* d_ws, size_t ws_size,
                              hipStream_t stream) {
    const int*   x       = (const int*)d_in[0];
    const int*   offsets = (const int*)d_in[1];
    const float* hw      = (const float*)d_in[2];
    const int*   widx    = (const int*)d_in[3];
    float*       out     = (float*)d_out;

    int total_tokens = in_sizes[0];
    int num_bags     = in_sizes[1];
    long long widx_elems = in_sizes[3];          // UPD * NUM_EMB * DIM
    long long emb_total  = widx_elems / 2;       // NUM_EMB * DIM

    size_t need = (size_t)emb_total * sizeof(float);

    if (ws_size >= need) {
        float* esum = (float*)d_ws;
        {
            long long nthreads = emb_total;
            int block = 256;
            long long grid = (nthreads + block - 1) / block;
            emb_sum_kernel<<<(int)grid, block, 0, stream>>>(widx, hw, esum, emb_total);
        }
        {
            int block = 256;
            int waves_per_block = block / 64;
            int grid = (num_bags + waves_per_block - 1) / waves_per_block;
            bag_sum_kernel<<<grid, block, 0, stream>>>(x, offsets, esum, out,
                                                       num_bags, total_tokens);
        }
    } else {
        int block = 256;
        int waves_per_block = block / 64;
        int grid = (num_bags + waves_per_block - 1) / waves_per_block;
        direct_kernel<<<grid, block, 0, stream>>>(x, offsets, hw, widx, out,
                                                  num_bags, total_tokens, emb_total);
    }
}

// Round 3
// 474.569 us; speedup vs baseline: 1.0088x; 1.0088x over previous
//
#include <hip/hip_runtime.h>

#define DIM 64

typedef int   vint4   __attribute__((ext_vector_type(4)));
typedef float vfloat4 __attribute__((ext_vector_type(4)));

// Phase 1: esum[g] = hw[widx[0][g]] + hw[widx[1][g]] for g in [0, total)
// 8 elements per thread: 16 independent gathers in flight (MLP), vec4
// nontemporal streaming for widx/esum so they don't evict hw from L2.
__global__ void emb_sum_kernel(const int* __restrict__ widx,
                               const float* __restrict__ hw,
                               float* __restrict__ esum,
                               long long total /* num_emb*DIM */) {
    long long base = ((long long)blockIdx.x * blockDim.x + threadIdx.x) * 8;
    if (base >= total) return;
    if (base + 8 <= total) {
        const vint4* w0 = (const vint4*)(widx + base);
        const vint4* w1 = (const vint4*)(widx + base + total);
        vint4 a0 = __builtin_nontemporal_load(w0);
        vint4 a1 = __builtin_nontemporal_load(w0 + 1);
        vint4 b0 = __builtin_nontemporal_load(w1);
        vint4 b1 = __builtin_nontemporal_load(w1 + 1);
        vfloat4 r0, r1;
        r0.x = hw[a0.x] + hw[b0.x];
        r0.y = hw[a0.y] + hw[b0.y];
        r0.z = hw[a0.z] + hw[b0.z];
        r0.w = hw[a0.w] + hw[b0.w];
        r1.x = hw[a1.x] + hw[b1.x];
        r1.y = hw[a1.y] + hw[b1.y];
        r1.z = hw[a1.z] + hw[b1.z];
        r1.w = hw[a1.w] + hw[b1.w];
        vfloat4* o = (vfloat4*)(esum + base);
        __builtin_nontemporal_store(r0, o);
        __builtin_nontemporal_store(r1, o + 1);
    } else {
        for (long long g = base; g < total; ++g)
            esum[g] = hw[widx[g]] + hw[widx[g + total]];
    }
}

// Phase 2: one wave per bag; lane = dim. 4 tokens processed per iteration
// with 4 independent accumulators -> 4 row-loads in flight per wave.
__global__ void bag_sum_kernel(const int* __restrict__ x,
                               const int* __restrict__ offsets,
                               const float* __restrict__ esum,
                               float* __restrict__ out,
                               int num_bags, int total_tokens) {
    int wave = (int)((blockIdx.x * blockDim.x + threadIdx.x) >> 6);
    int lane = threadIdx.x & 63;
    if (wave >= num_bags) return;
    int start = offsets[wave];
    int end = (wave + 1 < num_bags) ? offsets[wave + 1] : total_tokens;

    float acc0 = 0.0f, acc1 = 0.0f, acc2 = 0.0f, acc3 = 0.0f;
    for (int base = start; base < end; base += 64) {
        int n = end - base;
        if (n > 64) n = 64;
        int xv = (lane < n) ? x[base + lane] : 0;
        int t = 0;
        for (; t + 4 <= n; t += 4) {
            int e0 = __shfl(xv, t, 64);
            int e1 = __shfl(xv, t + 1, 64);
            int e2 = __shfl(xv, t + 2, 64);
            int e3 = __shfl(xv, t + 3, 64);
            float v0 = esum[(size_t)e0 * DIM + lane];
            float v1 = esum[(size_t)e1 * DIM + lane];
            float v2 = esum[(size_t)e2 * DIM + lane];
            float v3 = esum[(size_t)e3 * DIM + lane];
            acc0 += v0; acc1 += v1; acc2 += v2; acc3 += v3;
        }
        for (; t < n; ++t) {
            int e = __shfl(xv, t, 64);
            acc0 += esum[(size_t)e * DIM + lane];
        }
    }
    out[(size_t)wave * DIM + lane] = (acc0 + acc1) + (acc2 + acc3);
}

// Fallback: direct gather (no workspace). One wave per bag.
__global__ void direct_kernel(const int* __restrict__ x,
                              const int* __restrict__ offsets,
                              const float* __restrict__ hw,
                              const int* __restrict__ widx,
                              float* __restrict__ out,
                              int num_bags, int total_tokens,
                              long long emb_total) {
    int wave = (int)((blockIdx.x * blockDim.x + threadIdx.x) >> 6);
    int lane = threadIdx.x & 63;
    if (wave >= num_bags) return;
    int start = offsets[wave];
    int end = (wave + 1 < num_bags) ? offsets[wave + 1] : total_tokens;

    float acc = 0.0f;
    for (int t = start; t < end; ++t) {
        int e = x[t];
        const int* row = widx + (size_t)e * DIM;
        acc += hw[row[lane]] + hw[row[emb_total + lane]];
    }
    out[(size_t)wave * DIM + lane] = acc;
}

extern "C" void kernel_launch(void* const* d_in, const int* in_sizes, int n_in,
                              void* d_out, int out_size, void* d_ws, size_t ws_size,
                              hipStream_t stream) {
    const int*   x       = (const int*)d_in[0];
    const int*   offsets = (const int*)d_in[1];
    const float* hw      = (const float*)d_in[2];
    const int*   widx    = (const int*)d_in[3];
    float*       out     = (float*)d_out;

    int total_tokens = in_sizes[0];
    int num_bags     = in_sizes[1];
    long long widx_elems = in_sizes[3];          // UPD * NUM_EMB * DIM
    long long emb_total  = widx_elems / 2;       // NUM_EMB * DIM

    size_t need = (size_t)emb_total * sizeof(float);

    if (ws_size >= need) {
        float* esum = (float*)d_ws;
        {
            long long nthreads = (emb_total + 7) / 8;
            int block = 256;
            long long grid = (nthreads + block - 1) / block;
            emb_sum_kernel<<<(int)grid, block, 0, stream>>>(widx, hw, esum, emb_total);
        }
        {
            int block = 256;
            int waves_per_block = block / 64;
            int grid = (num_bags + waves_per_block - 1) / waves_per_block;
            bag_sum_kernel<<<grid, block, 0, stream>>>(x, offsets, esum, out,
                                                       num_bags, total_tokens);
        }
    } else {
        int block = 256;
        int waves_per_block = block / 64;
        int grid = (num_bags + waves_per_block - 1) / waves_per_block;
        direct_kernel<<<grid, block, 0, stream>>>(x, offsets, hw, widx, out,
                                                  num_bags, total_tokens, emb_total);
    }
}

// Round 4
// 346.931 us; speedup vs baseline: 1.3799x; 1.3679x over previous
//
#include <hip/hip_runtime.h>

#define DIM 64
#define K_PASSES 8

typedef int   vint4   __attribute__((ext_vector_type(4)));
typedef float vfloat4 __attribute__((ext_vector_type(4)));

// Phase 1: esum[g] = hw[widx[0][g]] + hw[widx[1][g]], g in [0,total).
// Cache-blocked: keep 16 indices + 8 accumulators in VGPRs, sweep hw in
// K_PASSES address slices sized to fit per-XCD L2 (12.8MB/8 = 1.6MB), so each
// hw line is fetched ~once per XCD instead of once per ~1.4 uses.
__global__ void emb_sum_kernel(const int* __restrict__ widx,
                               const float* __restrict__ hw,
                               float* __restrict__ esum,
                               long long total /* num_emb*DIM */,
                               int hashed_size) {
    long long base = ((long long)blockIdx.x * blockDim.x + threadIdx.x) * 8;
    if (base >= total) return;
    if (base + 8 <= total) {
        const vint4* w0 = (const vint4*)(widx + base);
        const vint4* w1 = (const vint4*)(widx + base + total);
        vint4 a0 = __builtin_nontemporal_load(w0);
        vint4 a1 = __builtin_nontemporal_load(w0 + 1);
        vint4 b0 = __builtin_nontemporal_load(w1);
        vint4 b1 = __builtin_nontemporal_load(w1 + 1);
        int idx[16] = {a0.x, a0.y, a0.z, a0.w, a1.x, a1.y, a1.z, a1.w,
                       b0.x, b0.y, b0.z, b0.w, b1.x, b1.y, b1.z, b1.w};
        float r[16];
#pragma unroll
        for (int i = 0; i < 16; ++i) r[i] = 0.0f;

        int slice = (hashed_size + K_PASSES - 1) / K_PASSES;
        int lo = 0;
        for (int k = 0; k < K_PASSES; ++k, lo += slice) {
#pragma unroll
            for (int i = 0; i < 16; ++i) {
                if ((unsigned)(idx[i] - lo) < (unsigned)slice)
                    r[i] += hw[idx[i]];
            }
        }
        vfloat4 o0 = {r[0] + r[8],  r[1] + r[9],  r[2] + r[10], r[3] + r[11]};
        vfloat4 o1 = {r[4] + r[12], r[5] + r[13], r[6] + r[14], r[7] + r[15]};
        vfloat4* o = (vfloat4*)(esum + base);
        __builtin_nontemporal_store(o0, o);
        __builtin_nontemporal_store(o1, o + 1);
    } else {
        for (long long g = base; g < total; ++g)
            esum[g] = hw[widx[g]] + hw[widx[g + total]];
    }
}

// Phase 2: one wave per bag. 4 token-groups of 16 lanes; each group loads one
// token row as float4 (64 lanes -> 4 rows / VMEM inst). Butterfly-reduce
// across groups at the end.
__global__ void bag_sum_kernel(const int* __restrict__ x,
                               const int* __restrict__ offsets,
                               const float* __restrict__ esum,
                               float* __restrict__ out,
                               int num_bags, int total_tokens) {
    int wave = (int)((blockIdx.x * blockDim.x + threadIdx.x) >> 6);
    int lane = threadIdx.x & 63;
    if (wave >= num_bags) return;
    int group = lane >> 4;   // 0..3
    int l16   = lane & 15;   // 0..15
    int start = offsets[wave];
    int end = (wave + 1 < num_bags) ? offsets[wave + 1] : total_tokens;

    vfloat4 acc = {0.0f, 0.0f, 0.0f, 0.0f};
    for (int base = start; base < end; base += 64) {
        int n = end - base;
        if (n > 64) n = 64;
        int xv = (lane < n) ? x[base + lane] : 0;
        int i = 0;
#pragma unroll 4
        for (; i + 4 <= n; i += 4) {
            int e = __shfl(xv, i + group, 64);
            const vfloat4* row = (const vfloat4*)(esum + (size_t)e * DIM);
            acc += row[l16];
        }
        if (i < n) {
            int src = i + group; if (src > n - 1) src = n - 1;
            int e = __shfl(xv, src, 64);
            vfloat4 v = ((const vfloat4*)(esum + (size_t)e * DIM))[l16];
            if (group < n - i) acc += v;
        }
    }
    // reduce across the 4 groups (lanes differing in bits 4,5)
    acc.x += __shfl_xor(acc.x, 16, 64);
    acc.y += __shfl_xor(acc.y, 16, 64);
    acc.z += __shfl_xor(acc.z, 16, 64);
    acc.w += __shfl_xor(acc.w, 16, 64);
    acc.x += __shfl_xor(acc.x, 32, 64);
    acc.y += __shfl_xor(acc.y, 32, 64);
    acc.z += __shfl_xor(acc.z, 32, 64);
    acc.w += __shfl_xor(acc.w, 32, 64);
    if (lane < 16)
        ((vfloat4*)(out + (size_t)wave * DIM))[l16] = acc;
}

// Fallback: direct gather (no workspace). One wave per bag.
__global__ void direct_kernel(const int* __restrict__ x,
                              const int* __restrict__ offsets,
                              const float* __restrict__ hw,
                              const int* __restrict__ widx,
                              float* __restrict__ out,
                              int num_bags, int total_tokens,
                              long long emb_total) {
    int wave = (int)((blockIdx.x * blockDim.x + threadIdx.x) >> 6);
    int lane = threadIdx.x & 63;
    if (wave >= num_bags) return;
    int start = offsets[wave];
    int end = (wave + 1 < num_bags) ? offsets[wave + 1] : total_tokens;

    float acc = 0.0f;
    for (int t = start; t < end; ++t) {
        int e = x[t];
        const int* row = widx + (size_t)e * DIM;
        acc += hw[row[lane]] + hw[row[emb_total + lane]];
    }
    out[(size_t)wave * DIM + lane] = acc;
}

extern "C" void kernel_launch(void* const* d_in, const int* in_sizes, int n_in,
                              void* d_out, int out_size, void* d_ws, size_t ws_size,
                              hipStream_t stream) {
    const int*   x       = (const int*)d_in[0];
    const int*   offsets = (const int*)d_in[1];
    const float* hw      = (const float*)d_in[2];
    const int*   widx    = (const int*)d_in[3];
    float*       out     = (float*)d_out;

    int total_tokens = in_sizes[0];
    int num_bags     = in_sizes[1];
    int hashed_size  = in_sizes[2];
    long long widx_elems = in_sizes[3];          // UPD * NUM_EMB * DIM
    long long emb_total  = widx_elems / 2;       // NUM_EMB * DIM

    size_t need = (size_t)emb_total * sizeof(float);

    if (ws_size >= need) {
        float* esum = (float*)d_ws;
        {
            long long nthreads = (emb_total + 7) / 8;
            int block = 256;
            long long grid = (nthreads + block - 1) / block;
            emb_sum_kernel<<<(int)grid, block, 0, stream>>>(widx, hw, esum,
                                                            emb_total, hashed_size);
        }
        {
            int block = 256;
            int waves_per_block = block / 64;
            int grid = (num_bags + waves_per_block - 1) / waves_per_block;
            bag_sum_kernel<<<grid, block, 0, stream>>>(x, offsets, esum, out,
                                                       num_bags, total_tokens);
        }
    } else {
        int block = 256;
        int waves_per_block = block / 64;
        int grid = (num_bags + waves_per_block - 1) / waves_per_block;
        direct_kernel<<<grid, block, 0, stream>>>(x, offsets, hw, widx, out,
                                                  num_bags, total_tokens, emb_total);
    }
}